// Round 11
// baseline (2061.609 us; speedup 1.0000x reference)
//
#include <hip/hip_runtime.h>
#include <hip/hip_bf16.h>
#include <math.h>

#define N_NODES 40000
#define NE      640000
#define FIN     33
#define H       128
#define COUT    3
#define NLAYERS 8
#define ALPHA   0.1f
#define THETA   0.5f
#define NPART   8
#define PSIZE   5000           // nodes per column partition (bf16 slice = 1.25 MB < 4 MiB L2)
#define CAP2    24             // per (part,row) capacity; deg ~ Poisson(2), P(>24) ~ 1e-13 overall

typedef __bf16 bf16x8 __attribute__((ext_vector_type(8)));
typedef float  f32x4  __attribute__((ext_vector_type(4)));

__device__ inline unsigned short f2bf(float f) {
    __hip_bfloat16 b = __float2bfloat16(f);
    return *(unsigned short*)&b;
}
__device__ inline float bf2f(unsigned short u) {
    __hip_bfloat16 b = *(__hip_bfloat16*)&u;
    return __bfloat162float(b);
}

// ---- partitioned bucket scatter: cell = p*N + row, p = col/PSIZE ----------
// edge record packed to 4 bytes: [bf16 weight*(1-alpha) | 16-bit col]
__global__ __launch_bounds__(256) void k_scatter(const int* __restrict__ row,
                          const int* __restrict__ col, const float* __restrict__ w,
                          int* __restrict__ cnt2, unsigned int* __restrict__ bucket2) {
    int e0 = (blockIdx.x * 256 + threadIdx.x) * 4;   // NE/1024 = 625 blocks exactly
    int cell[4], pos[4];
    unsigned int rec[4];
    #pragma unroll
    for (int i = 0; i < 4; i++) {
        int e = e0 + i;
        int r = row[e], c = col[e];
        cell[i] = (c / PSIZE) * N_NODES + r;
        unsigned int wb = f2bf((1.0f - ALPHA) * w[e]);
        rec[i] = (wb << 16) | (unsigned int)c;
    }
    #pragma unroll
    for (int i = 0; i < 4; i++) pos[i] = atomicAdd(&cnt2[cell[i]], 1);
    #pragma unroll
    for (int i = 0; i < 4; i++)
        if (pos[i] < CAP2) bucket2[(size_t)cell[i] * CAP2 + pos[i]] = rec[i];
}

// ---- Wtbf[l][j][k] = bf16(W[l][k][j])  (B operand for MFMA, row = output col)
__global__ __launch_bounds__(256) void k_wprep(const float* __restrict__ W,
                        unsigned short* __restrict__ Wtbf) {
    int idx = blockIdx.x * 256 + threadIdx.x;     // 8*128*128 = 131072
    int l = idx >> 14;
    int rem = idx & 16383;
    int k = rem >> 7, j = rem & 127;
    Wtbf[l * 16384 + j * 128 + k] = f2bf(W[idx]); // W[idx] = W[l][k][j], coalesced read
}

// ---- x0 = relu(x @ W_in^T + b_in); x0bf,hbf = bf16(x0); xx = alpha*x0 -----
__global__ __launch_bounds__(256) void k_xin(const float* __restrict__ x,
                      const float* __restrict__ Win, const float* __restrict__ bin,
                      unsigned short* __restrict__ x0bf,
                      unsigned short* __restrict__ hbf,
                      float* __restrict__ xx) {
    __shared__ float sW[H * FIN];      // 16.9 KB
    __shared__ float sx[16][FIN];      // 2.1 KB
    int t = threadIdx.x;
    for (int i = t; i < H * FIN; i += 256) sW[i] = Win[i];
    int n0 = blockIdx.x * 16;
    for (int i = t; i < 16 * FIN; i += 256)
        sx[i / FIN][i % FIN] = x[(size_t)(n0 + i / FIN) * FIN + (i % FIN)];
    __syncthreads();
    int f = t % H;
    int l0 = t / H;                    // 0..1
    float bv = bin[f];
    for (int lo = l0; lo < 16; lo += 2) {
        float acc = bv;
        #pragma unroll
        for (int k = 0; k < FIN; k++) acc += sx[lo][k] * sW[f * FIN + k];
        acc = fmaxf(acc, 0.f);
        size_t idx = (size_t)(n0 + lo) * H + f;
        unsigned short b = f2bf(acc);
        x0bf[idx] = b;
        hbf[idx] = b;
        xx[idx] = ALPHA * acc;         // seed layer-0 accumulator
    }
}

// ---- partition-ordered gather: xx[r] += sum_{e in bucket(p,r)} w*hbf[col] --
// wave per (p,row) cell; waves ordered p-major so each XCD's L2 holds the
// current 1.25 MB hbf slice. fp32 atomic flush (1 per lane-feature per cell).
__global__ __launch_bounds__(1024) void k_gather(const int* __restrict__ cnt2,
                       const unsigned int* __restrict__ bucket2,
                       const unsigned short* __restrict__ hbf,
                       float* __restrict__ xx) {
    int g = blockIdx.x * 16 + (threadIdx.x >> 6);    // cell id, p-major
    int lane = threadIdx.x & 63;
    int deg = cnt2[g];
    if (deg <= 0) return;                            // wave-uniform branch
    int r = g % N_NODES;
    const unsigned int* ep = bucket2 + (size_t)g * CAP2;
    float ax = 0.f, ay = 0.f, bx = 0.f, by = 0.f;
    float cx = 0.f, cy = 0.f, dx = 0.f, dy = 0.f;
    int e = 0;
    for (; e + 4 <= deg; e += 4) {
        unsigned int u0 = ep[e], u1 = ep[e + 1], u2 = ep[e + 2], u3 = ep[e + 3];
        __hip_bfloat162 v0 = ((const __hip_bfloat162*)(hbf + (size_t)(u0 & 0xffffu) * H))[lane];
        __hip_bfloat162 v1 = ((const __hip_bfloat162*)(hbf + (size_t)(u1 & 0xffffu) * H))[lane];
        __hip_bfloat162 v2 = ((const __hip_bfloat162*)(hbf + (size_t)(u2 & 0xffffu) * H))[lane];
        __hip_bfloat162 v3 = ((const __hip_bfloat162*)(hbf + (size_t)(u3 & 0xffffu) * H))[lane];
        float w0 = bf2f(u0 >> 16), w1 = bf2f(u1 >> 16);
        float w2 = bf2f(u2 >> 16), w3 = bf2f(u3 >> 16);
        ax += w0 * __bfloat162float(v0.x); ay += w0 * __bfloat162float(v0.y);
        bx += w1 * __bfloat162float(v1.x); by += w1 * __bfloat162float(v1.y);
        cx += w2 * __bfloat162float(v2.x); cy += w2 * __bfloat162float(v2.y);
        dx += w3 * __bfloat162float(v3.x); dy += w3 * __bfloat162float(v3.y);
    }
    if (e + 2 <= deg) {
        unsigned int u0 = ep[e], u1 = ep[e + 1];
        __hip_bfloat162 v0 = ((const __hip_bfloat162*)(hbf + (size_t)(u0 & 0xffffu) * H))[lane];
        __hip_bfloat162 v1 = ((const __hip_bfloat162*)(hbf + (size_t)(u1 & 0xffffu) * H))[lane];
        float w0 = bf2f(u0 >> 16), w1 = bf2f(u1 >> 16);
        ax += w0 * __bfloat162float(v0.x); ay += w0 * __bfloat162float(v0.y);
        bx += w1 * __bfloat162float(v1.x); by += w1 * __bfloat162float(v1.y);
        e += 2;
    }
    if (e < deg) {
        unsigned int u = ep[e];
        __hip_bfloat162 v = ((const __hip_bfloat162*)(hbf + (size_t)(u & 0xffffu) * H))[lane];
        float w = bf2f(u >> 16);
        cx += w * __bfloat162float(v.x); cy += w * __bfloat162float(v.y);
    }
    float sx = (ax + bx) + (cx + dx);
    float sy = (ay + by) + (cy + dy);
    atomicAdd(&xx[(size_t)r * H + lane * 2],     sx);
    atomicAdd(&xx[(size_t)r * H + lane * 2 + 1], sy);
}

// ---- MFMA GEMM + epilogue: hbf += relu((1-b)*xx + b*(xx@W));
// also re-seeds xx = alpha*x0 for the NEXT layer (safe: wave-lockstep, each
// element read(A-frag,skip) before its write; tiles disjoint across waves).
// do_out: last layer also emits out = h @ W_out^T + b_out.
__global__ __launch_bounds__(256) void k_gemm(float* __restrict__ xx,
                       const unsigned short* __restrict__ Wtbf,
                       unsigned short* __restrict__ hbf,
                       const unsigned short* __restrict__ x0bf, float beta,
                       const float* __restrict__ Wout, const float* __restrict__ bout,
                       float* __restrict__ out, int do_out) {
    int t = threadIdx.x;
    int wv = t >> 6, lane = t & 63;
    int quad = lane >> 4, l16 = lane & 15;
    int rbase = blockIdx.x * 64 + wv * 16;

    f32x4 acc[8];
    #pragma unroll
    for (int j = 0; j < 8; j++) acc[j] = (f32x4){0.f, 0.f, 0.f, 0.f};

    #pragma unroll
    for (int k0 = 0; k0 < 4; k0++) {
        const float* ap = xx + (size_t)(rbase + l16) * H + k0 * 32 + quad * 8;
        union { unsigned short u[8]; bf16x8 v; } af;
        #pragma unroll
        for (int i = 0; i < 8; i++) af.u[i] = f2bf(ap[i]);
        #pragma unroll
        for (int j = 0; j < 8; j++) {
            bf16x8 bv = *(const bf16x8*)(Wtbf + (size_t)(j * 16 + l16) * H + k0 * 32 + quad * 8);
            acc[j] = __builtin_amdgcn_mfma_f32_16x16x32_bf16(af.v, bv, acc[j], 0, 0, 0);
        }
    }

    float omb = 1.f - beta;
    float po[4][3];
    #pragma unroll
    for (int r = 0; r < 4; r++) { po[r][0] = 0.f; po[r][1] = 0.f; po[r][2] = 0.f; }

    #pragma unroll
    for (int j = 0; j < 8; j++) {
        int col = j * 16 + l16;
        float w0 = 0.f, w1 = 0.f, w2 = 0.f;
        if (do_out) { w0 = Wout[col]; w1 = Wout[H + col]; w2 = Wout[2 * H + col]; }
        #pragma unroll
        for (int r = 0; r < 4; r++) {
            int row = rbase + quad * 4 + r;        // C/D: row = quad*4 + reg
            size_t idx = (size_t)row * H + col;
            float sk = xx[idx];                    // fp32 skip term
            float o = omb * sk + beta * acc[j][r];
            float hv = bf2f(hbf[idx]) + fmaxf(o, 0.f);
            hbf[idx] = f2bf(hv);
            xx[idx] = ALPHA * bf2f(x0bf[idx]);     // seed next layer's accumulator
            po[r][0] += hv * w0; po[r][1] += hv * w1; po[r][2] += hv * w2;
        }
    }

    if (do_out) {
        #pragma unroll
        for (int off = 1; off < 16; off <<= 1) {
            #pragma unroll
            for (int r = 0; r < 4; r++) {
                po[r][0] += __shfl_xor(po[r][0], off);
                po[r][1] += __shfl_xor(po[r][1], off);
                po[r][2] += __shfl_xor(po[r][2], off);
            }
        }
        if (l16 == 0) {
            #pragma unroll
            for (int r = 0; r < 4; r++) {
                int row = rbase + quad * 4 + r;
                out[(size_t)row * 3 + 0] = po[r][0] + bout[0];
                out[(size_t)row * 3 + 1] = po[r][1] + bout[1];
                out[(size_t)row * 3 + 2] = po[r][2] + bout[2];
            }
        }
    }
}

extern "C" void kernel_launch(void* const* d_in, const int* in_sizes, int n_in,
                              void* d_out, int out_size, void* d_ws, size_t ws_size,
                              hipStream_t stream) {
    const float* x     = (const float*)d_in[0];
    const int*   erow  = (const int*)  d_in[1];
    const int*   ecol  = (const int*)  d_in[2];
    const float* ew    = (const float*)d_in[3];
    const float* Win   = (const float*)d_in[4];
    const float* bin   = (const float*)d_in[5];
    const float* Wout  = (const float*)d_in[6];
    const float* bout  = (const float*)d_in[7];
    const float* Wconv = (const float*)d_in[8];
    float* out = (float*)d_out;

    char* ws = (char*)d_ws;
    const size_t NHf = (size_t)N_NODES * H * sizeof(float);           // 20,480,000
    const size_t NHb = (size_t)N_NODES * H * sizeof(unsigned short);  // 10,240,000
    float*          xx    = (float*)(ws);
    unsigned short* x0bf  = (unsigned short*)(ws + NHf);
    unsigned short* hbf   = (unsigned short*)(ws + NHf + NHb);
    char* p = ws + NHf + 2 * NHb;
    unsigned short* Wtbf  = (unsigned short*)p;  p += 8 * H * H * 2;  // 262,144
    int*  cnt2    = (int*) p;  p += (size_t)NPART * N_NODES * 4;      // 1,280,000
    unsigned int* bucket2 = (unsigned int*)p;    // NPART*N*CAP2*4 = 30,720,000

    // partitioned bucket build: one memset + one scatter pass
    hipMemsetAsync(cnt2, 0, (size_t)NPART * N_NODES * 4, stream);
    k_scatter<<<NE / 1024, 256, 0, stream>>>(erow, ecol, ew, cnt2, bucket2);

    // weight prep + input projection (also seeds xx = alpha*x0)
    k_wprep<<<8 * H * H / 256, 256, 0, stream>>>(Wconv, Wtbf);
    k_xin  <<<N_NODES / 16,    256, 0, stream>>>(x, Win, bin, x0bf, hbf, xx);

    // layers: partition-ordered gather accumulates xx (fp32 atomics);
    // gemm finishes layer in place, refreshes hbf, re-seeds xx.
    const int GBLK = NPART * N_NODES / 16;       // 20000 blocks x 1024 threads
    for (int l = 0; l < NLAYERS; l++) {
        float beta = logf(THETA / (float)(l + 1) + 1.0f);
        k_gather<<<GBLK, 1024, 0, stream>>>(cnt2, bucket2, hbf, xx);
        k_gemm<<<N_NODES / 64, 256, 0, stream>>>(xx, Wtbf + (size_t)l * H * H,
                                                 hbf, x0bf, beta, Wout, bout, out,
                                                 (l == NLAYERS - 1) ? 1 : 0);
    }
}

// Round 12
// 485.891 us; speedup vs baseline: 4.2429x; 4.2429x over previous
//
#include <hip/hip_runtime.h>
#include <hip/hip_bf16.h>
#include <math.h>

#define N_NODES 40000
#define NE      640000
#define FIN     33
#define H       128
#define COUT    3
#define NLAYERS 8
#define ALPHA   0.1f
#define THETA   0.5f
#define CAP     96             // max bucket capacity; deg ~ Poisson(16), P(>96) ~ 1e-40

typedef __bf16 bf16x8 __attribute__((ext_vector_type(8)));
typedef float  f32x4  __attribute__((ext_vector_type(4)));

__device__ inline unsigned short f2bf(float f) {
    __hip_bfloat16 b = __float2bfloat16(f);
    return *(unsigned short*)&b;
}
__device__ inline float bf2f(unsigned short u) {
    __hip_bfloat16 b = *(__hip_bfloat16*)&u;
    return __bfloat162float(b);
}

// ---- bucket scatter: one pass, no prefix sum. 4 independent chains/thread.
// edge record packed to 4 bytes: [bf16 weight*(1-alpha) | 16-bit col]
__global__ __launch_bounds__(256) void k_scatter(const int* __restrict__ row,
                          const int* __restrict__ col, const float* __restrict__ w,
                          int* __restrict__ cnt, unsigned int* __restrict__ bucket) {
    int e0 = (blockIdx.x * 256 + threadIdx.x) * 4;   // NE/1024 = 625 blocks exactly
    int r[4], pos[4];
    unsigned int rec[4];
    #pragma unroll
    for (int i = 0; i < 4; i++) {
        int e = e0 + i;
        r[i] = row[e];
        unsigned int wb = f2bf((1.0f - ALPHA) * w[e]);
        rec[i] = (wb << 16) | (unsigned int)col[e];
    }
    #pragma unroll
    for (int i = 0; i < 4; i++) pos[i] = atomicAdd(&cnt[r[i]], 1);
    #pragma unroll
    for (int i = 0; i < 4; i++) bucket[(size_t)r[i] * CAP + pos[i]] = rec[i];
}

// ---- Wtbf[l][j][k] = bf16(W[l][k][j])  (B operand for MFMA, row = output col)
__global__ __launch_bounds__(256) void k_wprep(const float* __restrict__ W,
                        unsigned short* __restrict__ Wtbf) {
    int idx = blockIdx.x * 256 + threadIdx.x;     // 8*128*128 = 131072
    int l = idx >> 14;
    int rem = idx & 16383;
    int k = rem >> 7, j = rem & 127;
    Wtbf[l * 16384 + j * 128 + k] = f2bf(W[idx]); // W[idx] = W[l][k][j], coalesced read
}

// ---- x0 = relu(x @ W_in^T + b_in); x0bf, hbf = bf16(x0) -------------------
__global__ __launch_bounds__(256) void k_xin(const float* __restrict__ x,
                      const float* __restrict__ Win, const float* __restrict__ bin,
                      unsigned short* __restrict__ x0bf,
                      unsigned short* __restrict__ hbf) {
    __shared__ float sW[H * FIN];      // 16.9 KB
    __shared__ float sx[16][FIN];      // 2.1 KB
    int t = threadIdx.x;
    for (int i = t; i < H * FIN; i += 256) sW[i] = Win[i];
    int n0 = blockIdx.x * 16;
    for (int i = t; i < 16 * FIN; i += 256)
        sx[i / FIN][i % FIN] = x[(size_t)(n0 + i / FIN) * FIN + (i % FIN)];
    __syncthreads();
    int f = t % H;
    int l0 = t / H;                    // 0..1
    float bv = bin[f];
    for (int lo = l0; lo < 16; lo += 2) {
        float acc = bv;
        #pragma unroll
        for (int k = 0; k < FIN; k++) acc += sx[lo][k] * sW[f * FIN + k];
        acc = fmaxf(acc, 0.f);
        size_t idx = (size_t)(n0 + lo) * H + f;
        unsigned short b = f2bf(acc);
        x0bf[idx] = b;
        hbf[idx] = b;
    }
}

// ---- xx = A@hbf + alpha*x0bf -> bf16; wave/row, lane-group gathers --------
// 16 lanes cover one 256B row via dwordx4 (16B/lane): ONE load instruction
// gathers 4 edges' rows; 4 outstanding loads cover 16 edges -> a typical
// row (deg~16) completes in one latency round. Masked slots use u=0
// (w=0, col=0: reads row 0, L1-hot, contributes nothing).
__global__ __launch_bounds__(256) void k_spmm(const int* __restrict__ cnt,
                       const unsigned int* __restrict__ bucket,
                       const unsigned short* __restrict__ hbf,
                       const unsigned short* __restrict__ x0bf,
                       unsigned short* __restrict__ xxbf) {
    int wave = (blockIdx.x * blockDim.x + threadIdx.x) >> 6;
    int lane = threadIdx.x & 63;
    if (wave >= N_NODES) return;
    int deg = cnt[wave];
    const unsigned int* ep = bucket + (size_t)wave * CAP;
    int slot = lane >> 4;              // 0..3: edge within a group of 4
    int fid  = lane & 15;              // feature block: features fid*8 .. +7

    float acc[8] = {0,0,0,0,0,0,0,0};

    for (int base = 0; base < deg; base += 64) {
        int rem = deg - base; if (rem > 64) rem = 64;
        unsigned int ue = (lane < rem) ? ep[base + lane] : 0u;
        int steps = (rem + 15) >> 4;   // 1..4 pipeline steps of 16 edges
        for (int s = 0; s < steps; s++) {
            unsigned int u[4];
            uint4 q[4];
            #pragma unroll
            for (int k = 0; k < 4; k++) {
                int ei = s * 16 + k * 4 + slot;          // <= 63
                unsigned int uu = __shfl(ue, ei);
                u[k] = (ei < rem) ? uu : 0u;
            }
            #pragma unroll
            for (int k = 0; k < 4; k++)
                q[k] = *(const uint4*)(hbf + (size_t)(u[k] & 0xffffu) * H + fid * 8);
            #pragma unroll
            for (int k = 0; k < 4; k++) {
                float w = bf2f((unsigned short)(u[k] >> 16));
                acc[0] += w * bf2f((unsigned short)(q[k].x & 0xffffu));
                acc[1] += w * bf2f((unsigned short)(q[k].x >> 16));
                acc[2] += w * bf2f((unsigned short)(q[k].y & 0xffffu));
                acc[3] += w * bf2f((unsigned short)(q[k].y >> 16));
                acc[4] += w * bf2f((unsigned short)(q[k].z & 0xffffu));
                acc[5] += w * bf2f((unsigned short)(q[k].z >> 16));
                acc[6] += w * bf2f((unsigned short)(q[k].w & 0xffffu));
                acc[7] += w * bf2f((unsigned short)(q[k].w >> 16));
            }
        }
    }

    // reduce across the 4 slot-groups (lanes with equal fid)
    #pragma unroll
    for (int j = 0; j < 8; j++) {
        acc[j] += __shfl_xor(acc[j], 16);
        acc[j] += __shfl_xor(acc[j], 32);
    }

    if (slot == 0) {                    // lanes 0..15 hold the full row
        uint4 xq = *(const uint4*)(x0bf + (size_t)wave * H + fid * 8);
        float o0 = acc[0] + ALPHA * bf2f((unsigned short)(xq.x & 0xffffu));
        float o1 = acc[1] + ALPHA * bf2f((unsigned short)(xq.x >> 16));
        float o2 = acc[2] + ALPHA * bf2f((unsigned short)(xq.y & 0xffffu));
        float o3 = acc[3] + ALPHA * bf2f((unsigned short)(xq.y >> 16));
        float o4 = acc[4] + ALPHA * bf2f((unsigned short)(xq.z & 0xffffu));
        float o5 = acc[5] + ALPHA * bf2f((unsigned short)(xq.z >> 16));
        float o6 = acc[6] + ALPHA * bf2f((unsigned short)(xq.w & 0xffffu));
        float o7 = acc[7] + ALPHA * bf2f((unsigned short)(xq.w >> 16));
        uint4 r;
        r.x = (unsigned int)f2bf(o0) | ((unsigned int)f2bf(o1) << 16);
        r.y = (unsigned int)f2bf(o2) | ((unsigned int)f2bf(o3) << 16);
        r.z = (unsigned int)f2bf(o4) | ((unsigned int)f2bf(o5) << 16);
        r.w = (unsigned int)f2bf(o6) | ((unsigned int)f2bf(o7) << 16);
        *(uint4*)(xxbf + (size_t)wave * H + fid * 8) = r;
    }
}

// ---- MFMA GEMM + epilogue: hbf += relu((1-b)*xx + b*(xx@W))  (bf16 master)
// block = 4 waves, 64 rows; wave = 16 rows x 128 cols (8 16x16 acc tiles).
// do_out: also emit out = h @ W_out^T + b_out (last layer; fp32 hv in regs).
__global__ __launch_bounds__(256) void k_gemm(const unsigned short* __restrict__ xxbf,
                       const unsigned short* __restrict__ Wtbf,
                       unsigned short* __restrict__ hbf, float beta,
                       const float* __restrict__ Wout, const float* __restrict__ bout,
                       float* __restrict__ out, int do_out) {
    int t = threadIdx.x;
    int wv = t >> 6, lane = t & 63;
    int quad = lane >> 4, l16 = lane & 15;
    int rbase = blockIdx.x * 64 + wv * 16;

    f32x4 acc[8];
    #pragma unroll
    for (int j = 0; j < 8; j++) acc[j] = (f32x4){0.f, 0.f, 0.f, 0.f};

    #pragma unroll
    for (int k0 = 0; k0 < 4; k0++) {
        bf16x8 av = *(const bf16x8*)(xxbf + (size_t)(rbase + l16) * H + k0 * 32 + quad * 8);
        #pragma unroll
        for (int j = 0; j < 8; j++) {
            bf16x8 bv = *(const bf16x8*)(Wtbf + (size_t)(j * 16 + l16) * H + k0 * 32 + quad * 8);
            acc[j] = __builtin_amdgcn_mfma_f32_16x16x32_bf16(av, bv, acc[j], 0, 0, 0);
        }
    }

    float omb = 1.f - beta;
    float po[4][3];
    #pragma unroll
    for (int r = 0; r < 4; r++) { po[r][0] = 0.f; po[r][1] = 0.f; po[r][2] = 0.f; }

    #pragma unroll
    for (int j = 0; j < 8; j++) {
        int col = j * 16 + l16;
        float w0 = 0.f, w1 = 0.f, w2 = 0.f;
        if (do_out) { w0 = Wout[col]; w1 = Wout[H + col]; w2 = Wout[2 * H + col]; }
        #pragma unroll
        for (int r = 0; r < 4; r++) {
            int row = rbase + quad * 4 + r;        // C/D: row = quad*4 + reg
            size_t idx = (size_t)row * H + col;
            float sk = bf2f(xxbf[idx]);            // skip term (bf16)
            float o = omb * sk + beta * acc[j][r];
            float hv = bf2f(hbf[idx]) + fmaxf(o, 0.f);
            hbf[idx] = f2bf(hv);
            po[r][0] += hv * w0; po[r][1] += hv * w1; po[r][2] += hv * w2;
        }
    }

    if (do_out) {
        // reduce across the 16 lanes of each quad (xor strides stay in-quad)
        #pragma unroll
        for (int off = 1; off < 16; off <<= 1) {
            #pragma unroll
            for (int r = 0; r < 4; r++) {
                po[r][0] += __shfl_xor(po[r][0], off);
                po[r][1] += __shfl_xor(po[r][1], off);
                po[r][2] += __shfl_xor(po[r][2], off);
            }
        }
        if (l16 == 0) {
            #pragma unroll
            for (int r = 0; r < 4; r++) {
                int row = rbase + quad * 4 + r;
                out[(size_t)row * 3 + 0] = po[r][0] + bout[0];
                out[(size_t)row * 3 + 1] = po[r][1] + bout[1];
                out[(size_t)row * 3 + 2] = po[r][2] + bout[2];
            }
        }
    }
}

extern "C" void kernel_launch(void* const* d_in, const int* in_sizes, int n_in,
                              void* d_out, int out_size, void* d_ws, size_t ws_size,
                              hipStream_t stream) {
    const float* x     = (const float*)d_in[0];
    const int*   erow  = (const int*)  d_in[1];
    const int*   ecol  = (const int*)  d_in[2];
    const float* ew    = (const float*)d_in[3];
    const float* Win   = (const float*)d_in[4];
    const float* bin   = (const float*)d_in[5];
    const float* Wout  = (const float*)d_in[6];
    const float* bout  = (const float*)d_in[7];
    const float* Wconv = (const float*)d_in[8];
    float* out = (float*)d_out;

    char* ws = (char*)d_ws;
    const size_t NHb = (size_t)N_NODES * H * sizeof(unsigned short);  // 10,240,000
    unsigned short* xxbf  = (unsigned short*)(ws);
    unsigned short* x0bf  = (unsigned short*)(ws + NHb);
    unsigned short* hbf   = (unsigned short*)(ws + 2 * NHb);
    char* p = ws + 3 * NHb;
    unsigned short* Wtbf  = (unsigned short*)p;  p += 8 * H * H * 2;  // 262,144
    int*  cnt     = (int*) p;  p += 160256;                           // N ints, padded
    unsigned int* bucket = (unsigned int*)p;     // N * CAP * 4 = 15,360,000 B

    // bucket CSR build: one memset + one scatter (inputs restored every call)
    hipMemsetAsync(cnt, 0, (size_t)N_NODES * 4, stream);
    k_scatter<<<NE / 1024, 256, 0, stream>>>(erow, ecol, ew, cnt, bucket);

    // weight prep + input projection
    k_wprep<<<8 * H * H / 256, 256, 0, stream>>>(Wconv, Wtbf);
    k_xin  <<<N_NODES / 16,    256, 0, stream>>>(x, Win, bin, x0bf, hbf);

    // layers: spmm -> xxbf (bf16); gemm: hbf += relu(...) in place;
    // last layer's gemm also emits the output projection.
    for (int l = 0; l < NLAYERS; l++) {
        float beta = logf(THETA / (float)(l + 1) + 1.0f);
        k_spmm<<<N_NODES / 4,  256, 0, stream>>>(cnt, bucket, hbf, x0bf, xxbf);
        k_gemm<<<N_NODES / 64, 256, 0, stream>>>(xxbf, Wtbf + (size_t)l * H * H,
                                                 hbf, beta, Wout, bout, out,
                                                 (l == NLAYERS - 1) ? 1 : 0);
    }
}

// Round 13
// 469.820 us; speedup vs baseline: 4.3881x; 1.0342x over previous
//
#include <hip/hip_runtime.h>
#include <hip/hip_bf16.h>
#include <math.h>

#define N_NODES 40000
#define NE      640000
#define FIN     33
#define H       128
#define COUT    3
#define NLAYERS 8
#define ALPHA   0.1f
#define THETA   0.5f
#define CAP     96             // max bucket capacity; deg ~ Poisson(16), P(>96) ~ 1e-40

typedef __bf16 bf16x8 __attribute__((ext_vector_type(8)));
typedef float  f32x4  __attribute__((ext_vector_type(4)));

__device__ inline unsigned short f2bf(float f) {
    __hip_bfloat16 b = __float2bfloat16(f);
    return *(unsigned short*)&b;
}
__device__ inline float bf2f(unsigned short u) {
    __hip_bfloat16 b = *(__hip_bfloat16*)&u;
    return __bfloat162float(b);
}

// ---- bucket scatter: one pass, no prefix sum. 4 independent chains/thread.
// edge record packed to 4 bytes: [bf16 weight*(1-alpha) | 16-bit col]
__global__ __launch_bounds__(256) void k_scatter(const int* __restrict__ row,
                          const int* __restrict__ col, const float* __restrict__ w,
                          int* __restrict__ cnt, unsigned int* __restrict__ bucket) {
    int e0 = (blockIdx.x * 256 + threadIdx.x) * 4;   // NE/1024 = 625 blocks exactly
    int r[4], pos[4];
    unsigned int rec[4];
    #pragma unroll
    for (int i = 0; i < 4; i++) {
        int e = e0 + i;
        r[i] = row[e];
        unsigned int wb = f2bf((1.0f - ALPHA) * w[e]);
        rec[i] = (wb << 16) | (unsigned int)col[e];
    }
    #pragma unroll
    for (int i = 0; i < 4; i++) pos[i] = atomicAdd(&cnt[r[i]], 1);
    #pragma unroll
    for (int i = 0; i < 4; i++) bucket[(size_t)r[i] * CAP + pos[i]] = rec[i];
}

// ---- Wtbf[l][j][k] = bf16(W[l][k][j])  (B operand for MFMA, row = output col)
__global__ __launch_bounds__(256) void k_wprep(const float* __restrict__ W,
                        unsigned short* __restrict__ Wtbf) {
    int idx = blockIdx.x * 256 + threadIdx.x;     // 8*128*128 = 131072
    int l = idx >> 14;
    int rem = idx & 16383;
    int k = rem >> 7, j = rem & 127;
    Wtbf[l * 16384 + j * 128 + k] = f2bf(W[idx]); // W[idx] = W[l][k][j], coalesced read
}

// ---- x0 = relu(x @ W_in^T + b_in); x0bf, hbf = bf16(x0) -------------------
__global__ __launch_bounds__(256) void k_xin(const float* __restrict__ x,
                      const float* __restrict__ Win, const float* __restrict__ bin,
                      unsigned short* __restrict__ x0bf,
                      unsigned short* __restrict__ hbf) {
    __shared__ float sW[H * FIN];      // 16.9 KB
    __shared__ float sx[16][FIN];      // 2.1 KB
    int t = threadIdx.x;
    for (int i = t; i < H * FIN; i += 256) sW[i] = Win[i];
    int n0 = blockIdx.x * 16;
    for (int i = t; i < 16 * FIN; i += 256)
        sx[i / FIN][i % FIN] = x[(size_t)(n0 + i / FIN) * FIN + (i % FIN)];
    __syncthreads();
    int f = t % H;
    int l0 = t / H;                    // 0..1
    float bv = bin[f];
    for (int lo = l0; lo < 16; lo += 2) {
        float acc = bv;
        #pragma unroll
        for (int k = 0; k < FIN; k++) acc += sx[lo][k] * sW[f * FIN + k];
        acc = fmaxf(acc, 0.f);
        size_t idx = (size_t)(n0 + lo) * H + f;
        unsigned short b = f2bf(acc);
        x0bf[idx] = b;
        hbf[idx] = b;
    }
}

// ---- xx = A@hbf + alpha*x0bf -> bf16; wave/row, lane-group gathers --------
// 16 lanes cover one 256B row via dwordx4 (16B/lane). Edge records loaded
// DIRECTLY by each lane-group (16 lanes share one address -> single 16B
// fetch per 4-edge group, same VMEM stream as gathers, no shfl/LDS-pipe
// dependency). Masked slots use u=0 (w=0, col=0: L1-hot, contributes 0).
__global__ __launch_bounds__(256) void k_spmm(const int* __restrict__ cnt,
                       const unsigned int* __restrict__ bucket,
                       const unsigned short* __restrict__ hbf,
                       const unsigned short* __restrict__ x0bf,
                       unsigned short* __restrict__ xxbf) {
    int wave = (blockIdx.x * blockDim.x + threadIdx.x) >> 6;
    int lane = threadIdx.x & 63;
    if (wave >= N_NODES) return;
    int deg = cnt[wave];
    const unsigned int* ep = bucket + (size_t)wave * CAP;
    int slot = lane >> 4;              // 0..3: edge within a group of 4
    int fid  = lane & 15;              // feature block: features fid*8 .. +7

    float acc[8] = {0,0,0,0,0,0,0,0};

    for (int e = 0; e < deg; e += 16) {
        unsigned int u[4];
        uint4 q[4];
        #pragma unroll
        for (int k = 0; k < 4; k++) {
            int ei = e + k * 4 + slot;               // < CAP always (CAP%16==0)
            unsigned int uu = ep[ei];                // 16 lanes share address
            u[k] = (ei < deg) ? uu : 0u;
        }
        #pragma unroll
        for (int k = 0; k < 4; k++)
            q[k] = *(const uint4*)(hbf + (size_t)(u[k] & 0xffffu) * H + fid * 8);
        #pragma unroll
        for (int k = 0; k < 4; k++) {
            float w = bf2f((unsigned short)(u[k] >> 16));
            acc[0] += w * bf2f((unsigned short)(q[k].x & 0xffffu));
            acc[1] += w * bf2f((unsigned short)(q[k].x >> 16));
            acc[2] += w * bf2f((unsigned short)(q[k].y & 0xffffu));
            acc[3] += w * bf2f((unsigned short)(q[k].y >> 16));
            acc[4] += w * bf2f((unsigned short)(q[k].z & 0xffffu));
            acc[5] += w * bf2f((unsigned short)(q[k].z >> 16));
            acc[6] += w * bf2f((unsigned short)(q[k].w & 0xffffu));
            acc[7] += w * bf2f((unsigned short)(q[k].w >> 16));
        }
    }

    // reduce across the 4 slot-groups (lanes with equal fid)
    #pragma unroll
    for (int j = 0; j < 8; j++) {
        acc[j] += __shfl_xor(acc[j], 16);
        acc[j] += __shfl_xor(acc[j], 32);
    }

    if (slot == 0) {                    // lanes 0..15 hold the full row
        uint4 xq = *(const uint4*)(x0bf + (size_t)wave * H + fid * 8);
        float o0 = acc[0] + ALPHA * bf2f((unsigned short)(xq.x & 0xffffu));
        float o1 = acc[1] + ALPHA * bf2f((unsigned short)(xq.x >> 16));
        float o2 = acc[2] + ALPHA * bf2f((unsigned short)(xq.y & 0xffffu));
        float o3 = acc[3] + ALPHA * bf2f((unsigned short)(xq.y >> 16));
        float o4 = acc[4] + ALPHA * bf2f((unsigned short)(xq.z & 0xffffu));
        float o5 = acc[5] + ALPHA * bf2f((unsigned short)(xq.z >> 16));
        float o6 = acc[6] + ALPHA * bf2f((unsigned short)(xq.w & 0xffffu));
        float o7 = acc[7] + ALPHA * bf2f((unsigned short)(xq.w >> 16));
        uint4 r;
        r.x = (unsigned int)f2bf(o0) | ((unsigned int)f2bf(o1) << 16);
        r.y = (unsigned int)f2bf(o2) | ((unsigned int)f2bf(o3) << 16);
        r.z = (unsigned int)f2bf(o4) | ((unsigned int)f2bf(o5) << 16);
        r.w = (unsigned int)f2bf(o6) | ((unsigned int)f2bf(o7) << 16);
        *(uint4*)(xxbf + (size_t)wave * H + fid * 8) = r;
    }
}

// ---- MFMA GEMM + epilogue: hbf += relu((1-b)*xx + b*(xx@W))  (bf16 master)
// block = 2 waves (128 thr), 32 rows -> 1250 blocks for CU balance.
// wave = 16 rows x 128 cols (8 16x16 acc tiles).
// do_out: also emit out = h @ W_out^T + b_out (last layer; fp32 hv in regs).
__global__ __launch_bounds__(128) void k_gemm(const unsigned short* __restrict__ xxbf,
                       const unsigned short* __restrict__ Wtbf,
                       unsigned short* __restrict__ hbf, float beta,
                       const float* __restrict__ Wout, const float* __restrict__ bout,
                       float* __restrict__ out, int do_out) {
    int t = threadIdx.x;
    int wv = t >> 6, lane = t & 63;
    int quad = lane >> 4, l16 = lane & 15;
    int rbase = blockIdx.x * 32 + wv * 16;

    f32x4 acc[8];
    #pragma unroll
    for (int j = 0; j < 8; j++) acc[j] = (f32x4){0.f, 0.f, 0.f, 0.f};

    #pragma unroll
    for (int k0 = 0; k0 < 4; k0++) {
        bf16x8 av = *(const bf16x8*)(xxbf + (size_t)(rbase + l16) * H + k0 * 32 + quad * 8);
        #pragma unroll
        for (int j = 0; j < 8; j++) {
            bf16x8 bv = *(const bf16x8*)(Wtbf + (size_t)(j * 16 + l16) * H + k0 * 32 + quad * 8);
            acc[j] = __builtin_amdgcn_mfma_f32_16x16x32_bf16(av, bv, acc[j], 0, 0, 0);
        }
    }

    float omb = 1.f - beta;
    float po[4][3];
    #pragma unroll
    for (int r = 0; r < 4; r++) { po[r][0] = 0.f; po[r][1] = 0.f; po[r][2] = 0.f; }

    #pragma unroll
    for (int j = 0; j < 8; j++) {
        int col = j * 16 + l16;
        float w0 = 0.f, w1 = 0.f, w2 = 0.f;
        if (do_out) { w0 = Wout[col]; w1 = Wout[H + col]; w2 = Wout[2 * H + col]; }
        #pragma unroll
        for (int r = 0; r < 4; r++) {
            int row = rbase + quad * 4 + r;        // C/D: row = quad*4 + reg
            size_t idx = (size_t)row * H + col;
            float sk = bf2f(xxbf[idx]);            // skip term (bf16)
            float o = omb * sk + beta * acc[j][r];
            float hv = bf2f(hbf[idx]) + fmaxf(o, 0.f);
            hbf[idx] = f2bf(hv);
            po[r][0] += hv * w0; po[r][1] += hv * w1; po[r][2] += hv * w2;
        }
    }

    if (do_out) {
        // reduce across the 16 lanes of each quad (xor strides stay in-quad)
        #pragma unroll
        for (int off = 1; off < 16; off <<= 1) {
            #pragma unroll
            for (int r = 0; r < 4; r++) {
                po[r][0] += __shfl_xor(po[r][0], off);
                po[r][1] += __shfl_xor(po[r][1], off);
                po[r][2] += __shfl_xor(po[r][2], off);
            }
        }
        if (l16 == 0) {
            #pragma unroll
            for (int r = 0; r < 4; r++) {
                int row = rbase + quad * 4 + r;
                out[(size_t)row * 3 + 0] = po[r][0] + bout[0];
                out[(size_t)row * 3 + 1] = po[r][1] + bout[1];
                out[(size_t)row * 3 + 2] = po[r][2] + bout[2];
            }
        }
    }
}

extern "C" void kernel_launch(void* const* d_in, const int* in_sizes, int n_in,
                              void* d_out, int out_size, void* d_ws, size_t ws_size,
                              hipStream_t stream) {
    const float* x     = (const float*)d_in[0];
    const int*   erow  = (const int*)  d_in[1];
    const int*   ecol  = (const int*)  d_in[2];
    const float* ew    = (const float*)d_in[3];
    const float* Win   = (const float*)d_in[4];
    const float* bin   = (const float*)d_in[5];
    const float* Wout  = (const float*)d_in[6];
    const float* bout  = (const float*)d_in[7];
    const float* Wconv = (const float*)d_in[8];
    float* out = (float*)d_out;

    char* ws = (char*)d_ws;
    const size_t NHb = (size_t)N_NODES * H * sizeof(unsigned short);  // 10,240,000
    unsigned short* xxbf  = (unsigned short*)(ws);
    unsigned short* x0bf  = (unsigned short*)(ws + NHb);
    unsigned short* hbf   = (unsigned short*)(ws + 2 * NHb);
    char* p = ws + 3 * NHb;
    unsigned short* Wtbf  = (unsigned short*)p;  p += 8 * H * H * 2;  // 262,144
    int*  cnt     = (int*) p;  p += 160256;                           // N ints, padded
    unsigned int* bucket = (unsigned int*)p;     // N * CAP * 4 = 15,360,000 B

    // bucket CSR build: one memset + one scatter (inputs restored every call)
    hipMemsetAsync(cnt, 0, (size_t)N_NODES * 4, stream);
    k_scatter<<<NE / 1024, 256, 0, stream>>>(erow, ecol, ew, cnt, bucket);

    // weight prep + input projection
    k_wprep<<<8 * H * H / 256, 256, 0, stream>>>(Wconv, Wtbf);
    k_xin  <<<N_NODES / 16,    256, 0, stream>>>(x, Win, bin, x0bf, hbf);

    // layers: spmm -> xxbf (bf16); gemm: hbf += relu(...) in place;
    // last layer's gemm also emits the output projection.
    for (int l = 0; l < NLAYERS; l++) {
        float beta = logf(THETA / (float)(l + 1) + 1.0f);
        k_spmm<<<N_NODES / 4,  256, 0, stream>>>(cnt, bucket, hbf, x0bf, xxbf);
        k_gemm<<<N_NODES / 32, 128, 0, stream>>>(xxbf, Wtbf + (size_t)l * H * H,
                                                 hbf, beta, Wout, bout, out,
                                                 (l == NLAYERS - 1) ? 1 : 0);
    }
}

// Round 14
// 458.581 us; speedup vs baseline: 4.4956x; 1.0245x over previous
//
#include <hip/hip_runtime.h>
#include <hip/hip_bf16.h>
#include <math.h>

#define N_NODES 40000
#define NE      640000
#define FIN     33
#define H       128
#define COUT    3
#define NLAYERS 8
#define ALPHA   0.1f
#define THETA   0.5f
#define CAP     96             // max bucket capacity; deg ~ Poisson(16), P(>96) ~ 1e-40

// setup mega-kernel block ranges
#define SB_SCAT 625            // scatter: 625 blocks * 256 thr * 4 edges = 640000
#define SB_WPRE 512            // wprep:   512 blocks * 256 = 131072 elements
#define SB_XIN  2500           // xin:     2500 blocks * 16 nodes = 40000

typedef __bf16 bf16x8 __attribute__((ext_vector_type(8)));
typedef float  f32x4  __attribute__((ext_vector_type(4)));

__device__ inline unsigned short f2bf(float f) {
    __hip_bfloat16 b = __float2bfloat16(f);
    return *(unsigned short*)&b;
}
__device__ inline float bf2f(unsigned short u) {
    __hip_bfloat16 b = *(__hip_bfloat16*)&u;
    return __bfloat162float(b);
}

// ---- setup mega-kernel: [scatter | wprep(W-fold) | xin] by block range ----
// all three are mutually independent; merging saves 2 dispatch gaps and
// overlaps atomic-latency-bound scatter with compute-bound xin.
__global__ __launch_bounds__(256) void k_setup(
        const int* __restrict__ row, const int* __restrict__ col,
        const float* __restrict__ w, int* __restrict__ cnt,
        unsigned int* __restrict__ bucket,
        const float* __restrict__ Wconv, unsigned short* __restrict__ Wtbf,
        const float* __restrict__ x, const float* __restrict__ Win,
        const float* __restrict__ bin,
        unsigned short* __restrict__ x0bf, unsigned short* __restrict__ hbf) {
    __shared__ float sW[H * FIN];      // used by xin branch only (16.9 KB)
    __shared__ float sx[16][FIN];
    int b = blockIdx.x, t = threadIdx.x;

    if (b < SB_SCAT) {
        // bucket scatter: 4 independent chains/thread; record = [bf16 w | col]
        int e0 = (b * 256 + t) * 4;
        int r[4], pos[4];
        unsigned int rec[4];
        #pragma unroll
        for (int i = 0; i < 4; i++) {
            int e = e0 + i;
            r[i] = row[e];
            unsigned int wb = f2bf((1.0f - ALPHA) * w[e]);
            rec[i] = (wb << 16) | (unsigned int)col[e];
        }
        #pragma unroll
        for (int i = 0; i < 4; i++) pos[i] = atomicAdd(&cnt[r[i]], 1);
        #pragma unroll
        for (int i = 0; i < 4; i++) bucket[(size_t)r[i] * CAP + pos[i]] = rec[i];
        return;
    }
    if (b < SB_SCAT + SB_WPRE) {
        // W' = (1-beta)*I + beta*W, transposed to [l][j][k], bf16.
        // folds the GCN2 skip into the GEMM: (1-b)xx + b*xx@W = xx@W'
        int idx = (b - SB_SCAT) * 256 + t;        // = l*16384 + k*128 + j
        int l = idx >> 14;
        int rem = idx & 16383;
        int k = rem >> 7, j = rem & 127;
        float beta = logf(THETA / (float)(l + 1) + 1.0f);
        float v = beta * Wconv[idx];
        if (j == k) v += 1.0f - beta;
        Wtbf[l * 16384 + j * 128 + k] = f2bf(v);
        return;
    }
    {
        // x0 = relu(x @ W_in^T + b_in); x0bf, hbf = bf16(x0)
        int n0 = (b - SB_SCAT - SB_WPRE) * 16;
        for (int i = t; i < H * FIN; i += 256) sW[i] = Win[i];
        for (int i = t; i < 16 * FIN; i += 256)
            sx[i / FIN][i % FIN] = x[(size_t)(n0 + i / FIN) * FIN + (i % FIN)];
        __syncthreads();
        int f = t % H;
        int l0 = t / H;
        float bv = bin[f];
        for (int lo = l0; lo < 16; lo += 2) {
            float acc = bv;
            #pragma unroll
            for (int k = 0; k < FIN; k++) acc += sx[lo][k] * sW[f * FIN + k];
            acc = fmaxf(acc, 0.f);
            size_t idx = (size_t)(n0 + lo) * H + f;
            unsigned short bb = f2bf(acc);
            x0bf[idx] = bb;
            hbf[idx] = bb;
        }
    }
}

// ---- xx = A@hbf + alpha*x0bf -> bf16; wave/row, lane-group gathers --------
// 16 lanes cover one 256B row via dwordx4 (16B/lane); 4 edges per load instr.
__global__ __launch_bounds__(256) void k_spmm(const int* __restrict__ cnt,
                       const unsigned int* __restrict__ bucket,
                       const unsigned short* __restrict__ hbf,
                       const unsigned short* __restrict__ x0bf,
                       unsigned short* __restrict__ xxbf) {
    int wave = (blockIdx.x * blockDim.x + threadIdx.x) >> 6;
    int lane = threadIdx.x & 63;
    if (wave >= N_NODES) return;
    int deg = cnt[wave];
    const unsigned int* ep = bucket + (size_t)wave * CAP;
    int slot = lane >> 4;              // 0..3: edge within a group of 4
    int fid  = lane & 15;              // feature block: features fid*8 .. +7

    float acc[8] = {0,0,0,0,0,0,0,0};

    for (int e = 0; e < deg; e += 16) {
        unsigned int u[4];
        uint4 q[4];
        #pragma unroll
        for (int k = 0; k < 4; k++) {
            int ei = e + k * 4 + slot;               // < CAP always (CAP%16==0)
            unsigned int uu = ep[ei];                // 16 lanes share address
            u[k] = (ei < deg) ? uu : 0u;
        }
        #pragma unroll
        for (int k = 0; k < 4; k++)
            q[k] = *(const uint4*)(hbf + (size_t)(u[k] & 0xffffu) * H + fid * 8);
        #pragma unroll
        for (int k = 0; k < 4; k++) {
            float w = bf2f((unsigned short)(u[k] >> 16));
            acc[0] += w * bf2f((unsigned short)(q[k].x & 0xffffu));
            acc[1] += w * bf2f((unsigned short)(q[k].x >> 16));
            acc[2] += w * bf2f((unsigned short)(q[k].y & 0xffffu));
            acc[3] += w * bf2f((unsigned short)(q[k].y >> 16));
            acc[4] += w * bf2f((unsigned short)(q[k].z & 0xffffu));
            acc[5] += w * bf2f((unsigned short)(q[k].z >> 16));
            acc[6] += w * bf2f((unsigned short)(q[k].w & 0xffffu));
            acc[7] += w * bf2f((unsigned short)(q[k].w >> 16));
        }
    }

    // reduce across the 4 slot-groups (lanes with equal fid)
    #pragma unroll
    for (int j = 0; j < 8; j++) {
        acc[j] += __shfl_xor(acc[j], 16);
        acc[j] += __shfl_xor(acc[j], 32);
    }

    if (slot == 0) {                    // lanes 0..15 hold the full row
        uint4 xq = *(const uint4*)(x0bf + (size_t)wave * H + fid * 8);
        float o0 = acc[0] + ALPHA * bf2f((unsigned short)(xq.x & 0xffffu));
        float o1 = acc[1] + ALPHA * bf2f((unsigned short)(xq.x >> 16));
        float o2 = acc[2] + ALPHA * bf2f((unsigned short)(xq.y & 0xffffu));
        float o3 = acc[3] + ALPHA * bf2f((unsigned short)(xq.y >> 16));
        float o4 = acc[4] + ALPHA * bf2f((unsigned short)(xq.z & 0xffffu));
        float o5 = acc[5] + ALPHA * bf2f((unsigned short)(xq.z >> 16));
        float o6 = acc[6] + ALPHA * bf2f((unsigned short)(xq.w & 0xffffu));
        float o7 = acc[7] + ALPHA * bf2f((unsigned short)(xq.w >> 16));
        uint4 r;
        r.x = (unsigned int)f2bf(o0) | ((unsigned int)f2bf(o1) << 16);
        r.y = (unsigned int)f2bf(o2) | ((unsigned int)f2bf(o3) << 16);
        r.z = (unsigned int)f2bf(o4) | ((unsigned int)f2bf(o5) << 16);
        r.w = (unsigned int)f2bf(o6) | ((unsigned int)f2bf(o7) << 16);
        *(uint4*)(xxbf + (size_t)wave * H + fid * 8) = r;
    }
}

// ---- MFMA GEMM + epilogue: hbf += relu(xx @ W')   (skip folded into W')
// block = 2 waves (128 thr), 32 rows; wave = 16 rows x 128 cols.
// do_out: also emit out = h @ W_out^T + b_out (last layer; fp32 hv in regs).
__global__ __launch_bounds__(128) void k_gemm(const unsigned short* __restrict__ xxbf,
                       const unsigned short* __restrict__ Wtbf,
                       unsigned short* __restrict__ hbf,
                       const float* __restrict__ Wout, const float* __restrict__ bout,
                       float* __restrict__ out, int do_out) {
    int t = threadIdx.x;
    int wv = t >> 6, lane = t & 63;
    int quad = lane >> 4, l16 = lane & 15;
    int rbase = blockIdx.x * 32 + wv * 16;

    f32x4 acc[8];
    #pragma unroll
    for (int j = 0; j < 8; j++) acc[j] = (f32x4){0.f, 0.f, 0.f, 0.f};

    #pragma unroll
    for (int k0 = 0; k0 < 4; k0++) {
        bf16x8 av = *(const bf16x8*)(xxbf + (size_t)(rbase + l16) * H + k0 * 32 + quad * 8);
        #pragma unroll
        for (int j = 0; j < 8; j++) {
            bf16x8 bv = *(const bf16x8*)(Wtbf + (size_t)(j * 16 + l16) * H + k0 * 32 + quad * 8);
            acc[j] = __builtin_amdgcn_mfma_f32_16x16x32_bf16(av, bv, acc[j], 0, 0, 0);
        }
    }

    float po[4][3];
    #pragma unroll
    for (int r = 0; r < 4; r++) { po[r][0] = 0.f; po[r][1] = 0.f; po[r][2] = 0.f; }

    #pragma unroll
    for (int j = 0; j < 8; j++) {
        int col = j * 16 + l16;
        float w0 = 0.f, w1 = 0.f, w2 = 0.f;
        if (do_out) { w0 = Wout[col]; w1 = Wout[H + col]; w2 = Wout[2 * H + col]; }
        #pragma unroll
        for (int r = 0; r < 4; r++) {
            int row = rbase + quad * 4 + r;        // C/D: row = quad*4 + reg
            size_t idx = (size_t)row * H + col;
            float hv = bf2f(hbf[idx]) + fmaxf(acc[j][r], 0.f);
            hbf[idx] = f2bf(hv);
            po[r][0] += hv * w0; po[r][1] += hv * w1; po[r][2] += hv * w2;
        }
    }

    if (do_out) {
        // reduce across the 16 lanes of each quad (xor strides stay in-quad)
        #pragma unroll
        for (int off = 1; off < 16; off <<= 1) {
            #pragma unroll
            for (int r = 0; r < 4; r++) {
                po[r][0] += __shfl_xor(po[r][0], off);
                po[r][1] += __shfl_xor(po[r][1], off);
                po[r][2] += __shfl_xor(po[r][2], off);
            }
        }
        if (l16 == 0) {
            #pragma unroll
            for (int r = 0; r < 4; r++) {
                int row = rbase + quad * 4 + r;
                out[(size_t)row * 3 + 0] = po[r][0] + bout[0];
                out[(size_t)row * 3 + 1] = po[r][1] + bout[1];
                out[(size_t)row * 3 + 2] = po[r][2] + bout[2];
            }
        }
    }
}

extern "C" void kernel_launch(void* const* d_in, const int* in_sizes, int n_in,
                              void* d_out, int out_size, void* d_ws, size_t ws_size,
                              hipStream_t stream) {
    const float* x     = (const float*)d_in[0];
    const int*   erow  = (const int*)  d_in[1];
    const int*   ecol  = (const int*)  d_in[2];
    const float* ew    = (const float*)d_in[3];
    const float* Win   = (const float*)d_in[4];
    const float* bin   = (const float*)d_in[5];
    const float* Wout  = (const float*)d_in[6];
    const float* bout  = (const float*)d_in[7];
    const float* Wconv = (const float*)d_in[8];
    float* out = (float*)d_out;

    char* ws = (char*)d_ws;
    const size_t NHb = (size_t)N_NODES * H * sizeof(unsigned short);  // 10,240,000
    unsigned short* xxbf  = (unsigned short*)(ws);
    unsigned short* x0bf  = (unsigned short*)(ws + NHb);
    unsigned short* hbf   = (unsigned short*)(ws + 2 * NHb);
    char* p = ws + 3 * NHb;
    unsigned short* Wtbf  = (unsigned short*)p;  p += 8 * H * H * 2;  // 262,144
    int*  cnt     = (int*) p;  p += 160256;                           // N ints, padded
    unsigned int* bucket = (unsigned int*)p;     // N * CAP * 4 = 15,360,000 B

    // zero bucket counters, then one mega-dispatch: scatter + W-fold + xin
    hipMemsetAsync(cnt, 0, (size_t)N_NODES * 4, stream);
    k_setup<<<SB_SCAT + SB_WPRE + SB_XIN, 256, 0, stream>>>(
        erow, ecol, ew, cnt, bucket, Wconv, Wtbf, x, Win, bin, x0bf, hbf);

    // layers: spmm -> xxbf (bf16); gemm: hbf += relu(xx@W') in place;
    // last layer's gemm also emits the output projection.
    for (int l = 0; l < NLAYERS; l++) {
        k_spmm<<<N_NODES / 4,  256, 0, stream>>>(cnt, bucket, hbf, x0bf, xxbf);
        k_gemm<<<N_NODES / 32, 128, 0, stream>>>(xxbf, Wtbf + (size_t)l * H * H,
                                                 hbf, Wout, bout, out,
                                                 (l == NLAYERS - 1) ? 1 : 0);
    }
}